// Round 1
// baseline (8181.229 us; speedup 1.0000x reference)
//
#include <hip/hip_runtime.h>
#include <hip/hip_bf16.h>

#define V 10000
#define E 128
#define H1 128
#define H2 64
#define D 64
#define T 512
#define B 256
#define MAXLEN 30
#define SOS 1
#define EOS 2
#define BGS 8          // batch elements per pred task
#define NVB 40         // v-blocks in pred ((V+255)/256)
#define NBLK 256       // persistent blocks (1 per CU)

// converted-weight layout offsets (floats) inside ws
#define O_EMB   0
#define O_WIH1  1280000      // + V*E
#define O_WHH1  1378304      // + 512*192
#define O_BIH1  1443840      // + 512*128
#define O_BHH1  1444352      // + 512
#define O_WIH2  1444864      // + 512
#define O_WHH2  1477632      // + 256*128
#define O_BIH2  1494016      // + 256*64
#define O_BHH2  1494272      // + 256
#define O_WQ    1494528      // + 256
#define O_BQ    1498624      // + 64*64
#define O_WP    1498688      // + 64
#define O_BP    2778688      // + 10000*128
#define TOTALW  2788688      // + 10000

typedef unsigned long long u64;

__device__ __forceinline__ float b2f(__hip_bfloat16 x){ return __bfloat162float(x); }
__device__ __forceinline__ float sigf(float x){ return 1.f/(1.f + expf(-x)); }
__device__ __forceinline__ float4 ldf4(const float* p){
  float4 r; __builtin_memcpy(&r, (const void*)p, 16); return r;
}
__device__ __forceinline__ float dot4f(const float* x, float4 w){
  return x[0]*w.x + x[1]*w.y + x[2]*w.z + x[3]*w.w;
}

// ---------------------------------------------------------------------------
// grid barrier: monotonic ticket counter in ws. Release (__threadfence before
// arrive => wbL2 of this XCD) + acquire (__threadfence after => inv L1/L2)
// makes cross-XCD data visible. Spin-bail poisons bar[1] so a mis-dispatch
// fails instead of hanging.
// ---------------------------------------------------------------------------
__device__ __forceinline__ void gsync(unsigned* bar){
  __syncthreads();
  __threadfence();
  if (threadIdx.x == 0){
    const unsigned ticket = __hip_atomic_fetch_add(bar, 1u, __ATOMIC_ACQ_REL, __HIP_MEMORY_SCOPE_AGENT);
    const unsigned target = ticket - (ticket % (unsigned)NBLK) + (unsigned)NBLK;
    unsigned spins = 0u;
    while (__hip_atomic_load(bar, __ATOMIC_RELAXED, __HIP_MEMORY_SCOPE_AGENT) < target){
      if (__hip_atomic_load(bar + 1, __ATOMIC_RELAXED, __HIP_MEMORY_SCOPE_AGENT) != 0u) break;
      if (++spins > 30000000u){
        __hip_atomic_store(bar + 1, 1u, __ATOMIC_RELAXED, __HIP_MEMORY_SCOPE_AGENT);
        break;
      }
      __builtin_amdgcn_s_sleep(1);
    }
  }
  __syncthreads();
  __threadfence();
}

// ---------------------------------------------------------------------------
// kdtype: bf16 vs fp32 detection (unchanged, verified).
// ---------------------------------------------------------------------------
__global__ void kdtype(const void* __restrict__ probe, int* __restrict__ flagp){
  const int tid = threadIdx.x;                 // 64 threads
  const unsigned w = ((const unsigned*)probe)[tid];
  const unsigned e = (w >> 7) & 0xFFu;
  const bool inband = (e >= 0x60u) && (e <= 0x7Eu);
  const u64 m = __ballot(inband);
  if (tid == 0) flagp[0] = (m == 0xFFFFFFFFFFFFFFFFull) ? 1 : 0;
}

// ---------------------------------------------------------------------------
// kcvt: convert all weight tensors to fp32 into ws (unchanged, verified).
// ---------------------------------------------------------------------------
__global__ __launch_bounds__(256) void kcvt(
    const void* s_emb, const void* s_wih1, const void* s_whh1,
    const void* s_bih1, const void* s_bhh1, const void* s_wih2,
    const void* s_whh2, const void* s_bih2, const void* s_bhh2,
    const void* s_wq, const void* s_bq, const void* s_wp, const void* s_bp,
    float* __restrict__ dst, const int* __restrict__ flagp)
{
  const int idx = blockIdx.x * 256 + threadIdx.x;
  if (idx >= TOTALW) return;
  const int flag = flagp[0];
  const void* src; int off;
  if      (idx < O_WIH1){ src = s_emb;  off = idx - O_EMB;  }
  else if (idx < O_WHH1){ src = s_wih1; off = idx - O_WIH1; }
  else if (idx < O_BIH1){ src = s_whh1; off = idx - O_WHH1; }
  else if (idx < O_BHH1){ src = s_bih1; off = idx - O_BIH1; }
  else if (idx < O_WIH2){ src = s_bhh1; off = idx - O_BHH1; }
  else if (idx < O_WHH2){ src = s_wih2; off = idx - O_WIH2; }
  else if (idx < O_BIH2){ src = s_whh2; off = idx - O_WHH2; }
  else if (idx < O_BHH2){ src = s_bih2; off = idx - O_BIH2; }
  else if (idx < O_WQ)  { src = s_bhh2; off = idx - O_BHH2; }
  else if (idx < O_BQ)  { src = s_wq;   off = idx - O_WQ;   }
  else if (idx < O_WP)  { src = s_bq;   off = idx - O_BQ;   }
  else if (idx < O_BP)  { src = s_wp;   off = idx - O_WP;   }
  else                  { src = s_bp;   off = idx - O_BP;   }
  dst[idx] = flag ? b2f(((const __hip_bfloat16*)src)[off])
                  : ((const float*)src)[off];
}

// ---------------------------------------------------------------------------
// ktrans: enc_key/enc_val (T,B,D) -> fp32 (B,T,D); contiguous per-b streaming
// for the attention phase. Also resets the grid barrier each replay.
// ---------------------------------------------------------------------------
__global__ __launch_bounds__(256) void ktrans(
    const void* __restrict__ enc_key, const void* __restrict__ enc_val,
    float* __restrict__ encTk, float* __restrict__ encTv,
    const int* __restrict__ flagp, unsigned* __restrict__ bar)
{
  const int b = blockIdx.x;
  const int tid = threadIdx.x;
  if (b == 0 && tid < 16) bar[tid] = 0u;
  const int flag = flagp[0];
  const int d = tid & 63, tq = tid >> 6;
  if (flag){
    const __hip_bfloat16* bk = (const __hip_bfloat16*)enc_key;
    const __hip_bfloat16* bv = (const __hip_bfloat16*)enc_val;
    for (int tt = tq; tt < T; tt += 4){
      encTk[((size_t)b*T + tt)*D + d] = b2f(bk[((size_t)tt*B + b)*D + d]);
      encTv[((size_t)b*T + tt)*D + d] = b2f(bv[((size_t)tt*B + b)*D + d]);
    }
  } else {
    const float* fk = (const float*)enc_key;
    const float* fv = (const float*)enc_val;
    for (int tt = tq; tt < T; tt += 4){
      encTk[((size_t)b*T + tt)*D + d] = fk[((size_t)tt*B + b)*D + d];
      encTv[((size_t)b*T + tt)*D + d] = fv[((size_t)tt*B + b)*D + d];
    }
  }
}

// ---------------------------------------------------------------------------
// kmain: persistent kernel, all 30 steps. 256 blocks x 256 threads,
// 1 block/CU (LDS ~148 KB), 4 grid barriers per step.
//  G1: LSTM1 gates+update, tiled 8 row-tiles x 32 b-tiles, weights in LDS.
//  G2: LSTM2 gates+update, tiled 4 row-tiles x 64 b-tiles, weights in LDS.
//  G3: per-b query/attention/context from transposed fp32 enc.
//  G4: pred GEMV + argmax candidates (5 virtual kpred tasks per block).
// ---------------------------------------------------------------------------
__global__ __launch_bounds__(256) void kmain(
    const float* __restrict__ wts,
    const float* __restrict__ encTk, const float* __restrict__ encTv,
    const int* __restrict__ mask,
    void* __restrict__ outv,
    float* __restrict__ h1g,   // [2][B][H1]
    float* __restrict__ h2g,   // [2][B][H2]
    float* __restrict__ ctxg,  // [B][D]
    float* __restrict__ candv, int* __restrict__ candi,  // [B][NVB]
    unsigned* __restrict__ bar, const int* __restrict__ flagp)
{
  const int bid = blockIdx.x;
  const int tid = threadIdx.x;
  const int flagb = flagp[0];

  // role decompositions
  const int rt  = bid >> 5;        // 0..7  LSTM1 row-tile (16 units)
  const int bA  = (bid & 31) * 8;  // LSTM1 batch base (8 b)
  const int rt2 = bid >> 6;        // 0..3  LSTM2 row-tile (16 units)
  const int bB  = (bid & 63) * 4;  // LSTM2 batch base (4 b)

  // ---- LDS (total ~151.8 KB) ----
  __shared__ float4 wA4[80*64];              // 80 KB  [k4][r] LSTM1 weights
  __shared__ float4 wB4[48*64];              // 48 KB  [k4][r] LSTM2 weights
  __shared__ __align__(16) float xs[8*324];  // G1 xcat (emb|ctx|h1) / G4 xvec stage
  __shared__ __align__(16) float x2s[4*196]; // G2 xcat (h1new|h2prev)
  __shared__ float g_s[64*8];                // gates scratch
  __shared__ float c1_s[16*8];               // persistent c1 slice
  __shared__ float c2_s[16*4];               // persistent c2 slice
  __shared__ float bias1_s[64], bias2_s[64];
  __shared__ float q_s[D];
  __shared__ float h2b_s[H2];
  __shared__ float wv_s[T];
  __shared__ float red_s[256];
  __shared__ float lv_s[4*8]; __shared__ int li_s[4*8];
  __shared__ int tok_s[8];

  // ---- startup: stage persistent weights, zero state ----
  for (int idx = tid; idx < 80*64; idx += 256){
    const int k4 = idx >> 6, r = idx & 63;
    const int row = ((r >> 4) * 128) + (rt * 16) + (r & 15);
    float4 w;
    if (k4 < 48) w = ldf4(wts + O_WIH1 + (size_t)row*(E+D) + k4*4);
    else         w = ldf4(wts + O_WHH1 + (size_t)row*H1 + (k4-48)*4);
    wA4[idx] = w;
  }
  for (int idx = tid; idx < 48*64; idx += 256){
    const int k4 = idx >> 6, r = idx & 63;
    const int row = ((r >> 4) * 64) + (rt2 * 16) + (r & 15);
    float4 w;
    if (k4 < 32) w = ldf4(wts + O_WIH2 + (size_t)row*H1 + k4*4);
    else         w = ldf4(wts + O_WHH2 + (size_t)row*H2 + (k4-32)*4);
    wB4[idx] = w;
  }
  if (tid < 64){
    const int rowA = ((tid >> 4) * 128) + (rt * 16) + (tid & 15);
    bias1_s[tid] = wts[O_BIH1 + rowA] + wts[O_BHH1 + rowA];
    const int rowB = ((tid >> 4) * 64) + (rt2 * 16) + (tid & 15);
    bias2_s[tid] = wts[O_BIH2 + rowB] + wts[O_BHH2 + rowB];
  }
  if (tid < 128) c1_s[tid] = 0.f;
  if (tid < 64)  c2_s[tid] = 0.f;
  {
    const int b = bid;                       // zero "prev" (parity-1) state
    if (tid < H1) h1g[(size_t)B*H1 + (size_t)b*H1 + tid] = 0.f;
    if (tid < H2) h2g[(size_t)B*H2 + (size_t)b*H2 + tid] = 0.f;
    if (tid < D)  ctxg[(size_t)b*D + tid] = 0.f;
  }
  gsync(bar);

  for (int t = 0; t < MAXLEN; ++t){
    const int par = t & 1;
    const float* h1prev = h1g + (size_t)(par^1)*B*H1;
    float*       h1new  = h1g + (size_t)par*B*H1;
    const float* h2prev = h2g + (size_t)(par^1)*B*H2;
    float*       h2new  = h2g + (size_t)par*B*H2;

    // ================= G1: token argmax + LSTM1 =================
    if (t > 0){
      const int bi = tid >> 5, j = tid & 31;
      const int b = bA + bi;
      float mv = candv[b*NVB + j];
      int   mi = candi[b*NVB + j];
      if (j < NVB - 32){
        float ov = candv[b*NVB + j + 32]; int oi = candi[b*NVB + j + 32];
        if (ov > mv || (ov == mv && oi < mi)){ mv = ov; mi = oi; }
      }
      #pragma unroll
      for (int off = 16; off > 0; off >>= 1){
        float ov = __shfl_down(mv, off); int oi = __shfl_down(mi, off);
        if (ov > mv || (ov == mv && oi < mi)){ mv = ov; mi = oi; }
      }
      if (j == 0) tok_s[bi] = mi;
    } else {
      if (tid < 8) tok_s[tid] = SOS;
    }
    __syncthreads();

    // xcat = [emb(128) | ctx(64) | h1prev(128)] per b, padded rows of 324
    for (int bi = 0; bi < 8; ++bi){
      const int b = bA + bi;
      const int tok = tok_s[bi];
      for (int k = tid; k < 320; k += 256){
        float x;
        if (k < E)          x = (tok == EOS) ? 0.f : wts[O_EMB + (size_t)tok*E + k];
        else if (k < E + D) x = ctxg[(size_t)b*D + (k - E)];
        else                x = h1prev[(size_t)b*H1 + (k - (E + D))];
        xs[bi*324 + k] = x;
      }
    }
    __syncthreads();

    {
      const int r = tid >> 2, bq = tid & 3;          // 64 rows x 4 b-pairs
      const float4* x0 = (const float4*)(xs + (bq*2    )*324);
      const float4* x1 = (const float4*)(xs + (bq*2 + 1)*324);
      float a0 = bias1_s[r], a1 = a0;
      #pragma unroll 8
      for (int k4 = 0; k4 < 80; ++k4){
        const float4 w = wA4[k4*64 + r];
        const float4 xa = x0[k4], xb = x1[k4];
        a0 += xa.x*w.x + xa.y*w.y + xa.z*w.z + xa.w*w.w;
        a1 += xb.x*w.x + xb.y*w.y + xb.z*w.z + xb.w*w.w;
      }
      g_s[r*8 + bq*2]     = a0;
      g_s[r*8 + bq*2 + 1] = a1;
    }
    __syncthreads();
    if (tid < 128){
      const int ui = tid >> 3, bi = tid & 7;
      const float gi = sigf (g_s[(ui     )*8 + bi]);
      const float gf = sigf (g_s[(16 + ui)*8 + bi]);
      const float gg = tanhf(g_s[(32 + ui)*8 + bi]);
      const float go = sigf (g_s[(48 + ui)*8 + bi]);
      const float cn = gf * c1_s[ui*8 + bi] + gi * gg;
      c1_s[ui*8 + bi] = cn;
      h1new[(size_t)(bA + bi)*H1 + rt*16 + ui] = go * tanhf(cn);
    }
    gsync(bar);

    // ================= G2: LSTM2 =================
    {
      const int bi = tid >> 6, k0 = tid & 63;        // 4 b x 64 lanes
      #pragma unroll
      for (int kk = k0; kk < 192; kk += 64){
        float x = (kk < H1) ? h1new[(size_t)(bB + bi)*H1 + kk]
                            : h2prev[(size_t)(bB + bi)*H2 + (kk - H1)];
        x2s[bi*196 + kk] = x;
      }
    }
    __syncthreads();
    {
      const int r = tid >> 2, bq = tid & 3;          // 64 rows x 4 b
      const float4* xp = (const float4*)(x2s + bq*196);
      float a = bias2_s[r];
      #pragma unroll 8
      for (int k4 = 0; k4 < 48; ++k4){
        const float4 w = wB4[k4*64 + r];
        const float4 x = xp[k4];
        a += x.x*w.x + x.y*w.y + x.z*w.z + x.w*w.w;
      }
      g_s[r*8 + bq] = a;
    }
    __syncthreads();
    if (tid < 64){
      const int ui = tid >> 2, bi = tid & 3;
      const float gi = sigf (g_s[(ui     )*8 + bi]);
      const float gf = sigf (g_s[(16 + ui)*8 + bi]);
      const float gg = tanhf(g_s[(32 + ui)*8 + bi]);
      const float go = sigf (g_s[(48 + ui)*8 + bi]);
      const float cn = gf * c2_s[ui*4 + bi] + gi * gg;
      c2_s[ui*4 + bi] = cn;
      h2new[(size_t)(bB + bi)*H2 + rt2*16 + ui] = go * tanhf(cn);
    }
    gsync(bar);

    // ================= G3: query + attention + context (b = bid) =================
    {
      const int b = bid;
      if (tid < H2) h2b_s[tid] = h2new[(size_t)b*H2 + tid];
      __syncthreads();
      if (tid < D){
        const float* wr = wts + O_WQ + (size_t)tid*H2;
        float acc = wts[O_BQ + tid];
        #pragma unroll
        for (int kk = 0; kk < H2/4; ++kk) acc += dot4f(h2b_s + kk*4, ldf4(wr + kk*4));
        q_s[tid] = acc;
      }
      __syncthreads();
      float e0 = 0.f, e1 = 0.f;
      const float* kr0 = encTk + ((size_t)b*T + tid)*D;
      const float* kr1 = kr0 + (size_t)256*D;
      #pragma unroll
      for (int kk = 0; kk < D/4; ++kk){
        e0 += dot4f(q_s + kk*4, ldf4(kr0 + kk*4));
        e1 += dot4f(q_s + kk*4, ldf4(kr1 + kk*4));
      }
      red_s[tid] = fmaxf(e0, e1);
      __syncthreads();
      for (int s = 128; s > 0; s >>= 1){
        if (tid < s) red_s[tid] = fmaxf(red_s[tid], red_s[tid + s]);
        __syncthreads();
      }
      const float emax = red_s[0];
      __syncthreads();
      const int m0 = mask[b*T + tid], m1 = mask[b*T + tid + 256];
      const float w0 = m0 ? expf(e0 - emax) : 0.f;
      const float w1 = m1 ? expf(e1 - emax) : 0.f;
      wv_s[tid] = w0;
      wv_s[tid + 256] = w1;
      red_s[tid] = w0 + w1;
      __syncthreads();
      for (int s = 128; s > 0; s >>= 1){
        if (tid < s) red_s[tid] += red_s[tid + s];
        __syncthreads();
      }
      const float inv = 1.f / fmaxf(red_s[0], 2e-30f);
      __syncthreads();
      {
        const int d = tid & 63, ch = tid >> 6;
        const float* vb2 = encTv + (size_t)b*T*D + d;
        float acc = 0.f;
        #pragma unroll 8
        for (int tt = ch*128; tt < ch*128 + 128; ++tt)
          acc += wv_s[tt] * vb2[(size_t)tt*D];
        red_s[tid] = acc;
      }
      __syncthreads();
      if (tid < D)
        ctxg[(size_t)b*D + tid] =
            (red_s[tid] + red_s[tid+64] + red_s[tid+128] + red_s[tid+192]) * inv;
    }
    gsync(bar);

    // ================= G4: pred + argmax candidates (5 virtual tasks) =================
    for (int i = 0; i < 5; ++i){
      const int tau = i*256 + bid;
      const int vb = tau % NVB;            // block-uniform
      const int bg = tau / NVB;
      // stage xvec = [h2new | ctx] for 8 b's into LDS
      {
        const int bi = tid >> 5, kq = tid & 31;
        const int b = bg*BGS + bi;
        const int k = kq * 4;
        float4 x;
        if (k < H2) x = ldf4(h2new + (size_t)b*H2 + k);
        else        x = ldf4(ctxg + (size_t)b*D + (k - H2));
        *(float4*)(xs + bi*324 + k) = x;
      }
      __syncthreads();

      const int v = vb*256 + tid;
      const bool valid = v < V;
      const int vc = valid ? v : 0;
      const float* wrow = wts + O_WP + (size_t)vc*(H2 + D);
      float acc[BGS];
      #pragma unroll
      for (int q = 0; q < BGS; ++q) acc[q] = 0.f;
      #pragma unroll 8
      for (int kk = 0; kk < (H2 + D)/4; ++kk){
        const float4 w = ldf4(wrow + kk*4);
        #pragma unroll
        for (int q = 0; q < BGS; ++q){
          const float4 x = *(const float4*)(xs + q*324 + kk*4);
          acc[q] += x.x*w.x + x.y*w.y + x.z*w.z + x.w*w.w;
        }
      }
      const float bias = valid ? wts[O_BP + vc] : 0.f;
      #pragma unroll
      for (int q = 0; q < BGS; ++q){
        acc[q] += bias;
        if (valid){
          const size_t oi = ((size_t)(bg*BGS + q)*MAXLEN + t)*V + v;
          if (flagb){
            __hip_bfloat16 hv = __float2bfloat16(acc[q]);
            unsigned short us; __builtin_memcpy(&us, &hv, 2);
            __builtin_nontemporal_store(us, (unsigned short*)outv + oi);
          } else {
            __builtin_nontemporal_store(acc[q], (float*)outv + oi);
          }
        }
      }
      // per-b (val, idx) max, first-index tie-break
      const int lane = tid & 63, wid = tid >> 6;
      #pragma unroll
      for (int q = 0; q < BGS; ++q){
        float mv = valid ? acc[q] : -__builtin_inff();
        int   mi = valid ? v : 0x7FFFFFFF;
        for (int off = 32; off > 0; off >>= 1){
          float ov = __shfl_down(mv, off);
          int   oi = __shfl_down(mi, off);
          if (ov > mv || (ov == mv && oi < mi)){ mv = ov; mi = oi; }
        }
        if (lane == 0){ lv_s[wid*8 + q] = mv; li_s[wid*8 + q] = mi; }
      }
      __syncthreads();
      if (tid < BGS){
        float mv = lv_s[tid]; int mi = li_s[tid];
        #pragma unroll
        for (int w2 = 1; w2 < 4; ++w2){
          float ov = lv_s[w2*8 + tid]; int oi = li_s[w2*8 + tid];
          if (ov > mv || (ov == mv && oi < mi)){ mv = ov; mi = oi; }
        }
        const int b = bg*BGS + tid;
        candv[b*NVB + vb] = mv;
        candi[b*NVB + vb] = mi;
      }
      __syncthreads();
    }
    gsync(bar);
  }
}

// ---------------------------------------------------------------------------
extern "C" void kernel_launch(void* const* d_in, const int* in_sizes, int n_in,
                              void* d_out, int out_size, void* d_ws, size_t ws_size,
                              hipStream_t stream)
{
  const void* enc_key = d_in[0];
  const void* enc_val = d_in[1];
  const int*  mask    = (const int*)d_in[2];
  const void* emb     = d_in[3];
  const void* w_ih1   = d_in[4];
  const void* w_hh1   = d_in[5];
  const void* b_ih1   = d_in[6];
  const void* b_hh1   = d_in[7];
  const void* w_ih2   = d_in[8];
  const void* w_hh2   = d_in[9];
  const void* b_ih2   = d_in[10];
  const void* b_hh2   = d_in[11];
  const void* wq      = d_in[12];
  const void* bq      = d_in[13];
  const void* wp      = d_in[14];
  const void* bp      = d_in[15];

  // ws layout: [flag 16f][wts TOTALW][h1g 2*B*H1][h2g 2*B*H2][ctx B*D]
  //            [candv B*NVB][candi B*NVB][bar 16u][encTk B*T*D][encTv B*T*D]
  float* wsf  = (float*)d_ws;
  int*  flagp = (int*)wsf;
  float* wts  = wsf + 16;
  float* h1g   = wts + TOTALW;
  float* h2g   = h1g + 2*B*H1;
  float* ctxg  = h2g + 2*B*H2;
  float* candv = ctxg + B*D;
  int*   candi = (int*)(candv + B*NVB);
  unsigned* bar = (unsigned*)(candi + B*NVB);
  float* encTk = (float*)(bar + 16);
  float* encTv = encTk + (size_t)B*T*D;

  kdtype<<<dim3(1), dim3(64), 0, stream>>>(b_ih1, flagp);
  kcvt<<<dim3((TOTALW + 255)/256), dim3(256), 0, stream>>>(
      emb, w_ih1, w_hh1, b_ih1, b_hh1, w_ih2, w_hh2, b_ih2, b_hh2,
      wq, bq, wp, bp, wts, flagp);
  ktrans<<<dim3(B), dim3(256), 0, stream>>>(enc_key, enc_val, encTk, encTv, flagp, bar);

  // Persistent kernel: 256 blocks x 256 threads, ~148 KB LDS => exactly
  // 1 block/CU on 256 CUs; all blocks co-resident, so the hand-rolled grid
  // barrier is safe with a plain launch (no cooperative API needed inside
  // graph capture). Spin-bail in gsync guards against pathological dispatch.
  kmain<<<dim3(NBLK), dim3(256), 0, stream>>>(
      wts, encTk, encTv, mask, d_out,
      h1g, h2g, ctxg, candv, candi, bar, flagp);
}

// Round 2
// 3191.996 us; speedup vs baseline: 2.5630x; 2.5630x over previous
//
#include <hip/hip_runtime.h>
#include <hip/hip_bf16.h>

#define V 10000
#define E 128
#define H1 128
#define H2 64
#define D 64
#define T 512
#define B 256
#define MAXLEN 30
#define SOS 1
#define EOS 2
#define BGS 8          // batch elements per pred task
#define NVB 40         // v-blocks in pred ((V+255)/256)

// converted-weight layout offsets (floats) inside ws
#define O_EMB   0
#define O_WIH1  1280000      // + V*E
#define O_WHH1  1378304      // + 512*192
#define O_BIH1  1443840      // + 512*128
#define O_BHH1  1444352      // + 512
#define O_WIH2  1444864      // + 512
#define O_WHH2  1477632      // + 256*128
#define O_BIH2  1494016      // + 256*64
#define O_BHH2  1494272      // + 256
#define O_WQ    1494528      // + 256
#define O_BQ    1498624      // + 64*64
#define O_WP    1498688      // + 64
#define O_BP    2778688      // + 10000*128
#define TOTALW  2788688      // + 10000

typedef unsigned long long u64;

__device__ __forceinline__ float b2f(__hip_bfloat16 x){ return __bfloat162float(x); }
__device__ __forceinline__ float sigf(float x){ return 1.f/(1.f + expf(-x)); }
__device__ __forceinline__ float4 ldf4(const float* p){
  float4 r; __builtin_memcpy(&r, (const void*)p, 16); return r;
}
__device__ __forceinline__ float dot4f(const float* x, float4 w){
  return x[0]*w.x + x[1]*w.y + x[2]*w.z + x[3]*w.w;
}

// ---------------------------------------------------------------------------
// kdtype: bf16 vs fp32 detection (unchanged, verified).
// ---------------------------------------------------------------------------
__global__ void kdtype(const void* __restrict__ probe, int* __restrict__ flagp){
  const int tid = threadIdx.x;                 // 64 threads
  const unsigned w = ((const unsigned*)probe)[tid];
  const unsigned e = (w >> 7) & 0xFFu;
  const bool inband = (e >= 0x60u) && (e <= 0x7Eu);
  const u64 m = __ballot(inband);
  if (tid == 0) flagp[0] = (m == 0xFFFFFFFFFFFFFFFFull) ? 1 : 0;
}

// ---------------------------------------------------------------------------
// kcvt: convert all weight tensors to fp32 into ws (unchanged, verified).
// ---------------------------------------------------------------------------
__global__ __launch_bounds__(256) void kcvt(
    const void* s_emb, const void* s_wih1, const void* s_whh1,
    const void* s_bih1, const void* s_bhh1, const void* s_wih2,
    const void* s_whh2, const void* s_bih2, const void* s_bhh2,
    const void* s_wq, const void* s_bq, const void* s_wp, const void* s_bp,
    float* __restrict__ dst, const int* __restrict__ flagp)
{
  const int idx = blockIdx.x * 256 + threadIdx.x;
  if (idx >= TOTALW) return;
  const int flag = flagp[0];
  const void* src; int off;
  if      (idx < O_WIH1){ src = s_emb;  off = idx - O_EMB;  }
  else if (idx < O_WHH1){ src = s_wih1; off = idx - O_WIH1; }
  else if (idx < O_BIH1){ src = s_whh1; off = idx - O_WHH1; }
  else if (idx < O_BHH1){ src = s_bih1; off = idx - O_BIH1; }
  else if (idx < O_WIH2){ src = s_bhh1; off = idx - O_BHH1; }
  else if (idx < O_WHH2){ src = s_wih2; off = idx - O_WIH2; }
  else if (idx < O_BIH2){ src = s_whh2; off = idx - O_WHH2; }
  else if (idx < O_BHH2){ src = s_bih2; off = idx - O_BIH2; }
  else if (idx < O_WQ)  { src = s_bhh2; off = idx - O_BHH2; }
  else if (idx < O_BQ)  { src = s_wq;   off = idx - O_WQ;   }
  else if (idx < O_WP)  { src = s_bq;   off = idx - O_BQ;   }
  else if (idx < O_BP)  { src = s_wp;   off = idx - O_WP;   }
  else                  { src = s_bp;   off = idx - O_BP;   }
  dst[idx] = flag ? b2f(((const __hip_bfloat16*)src)[off])
                  : ((const float*)src)[off];
}

// ---------------------------------------------------------------------------
// ktrans: enc_key/enc_val (T,B,D) -> fp32 (B,T,D); contiguous per-b streaming
// for the attention phase (verified in round-1 kmain G3).
// ---------------------------------------------------------------------------
__global__ __launch_bounds__(256) void ktrans(
    const void* __restrict__ enc_key, const void* __restrict__ enc_val,
    float* __restrict__ encTk, float* __restrict__ encTv,
    const int* __restrict__ flagp)
{
  const int b = blockIdx.x;
  const int tid = threadIdx.x;
  const int flag = flagp[0];
  const int d = tid & 63, tq = tid >> 6;
  if (flag){
    const __hip_bfloat16* bk = (const __hip_bfloat16*)enc_key;
    const __hip_bfloat16* bv = (const __hip_bfloat16*)enc_val;
    for (int tt = tq; tt < T; tt += 4){
      encTk[((size_t)b*T + tt)*D + d] = b2f(bk[((size_t)tt*B + b)*D + d]);
      encTv[((size_t)b*T + tt)*D + d] = b2f(bv[((size_t)tt*B + b)*D + d]);
    }
  } else {
    const float* fk = (const float*)enc_key;
    const float* fv = (const float*)enc_val;
    for (int tt = tq; tt < T; tt += 4){
      encTk[((size_t)b*T + tt)*D + d] = fk[((size_t)tt*B + b)*D + d];
      encTv[((size_t)b*T + tt)*D + d] = fv[((size_t)tt*B + b)*D + d];
    }
  }
}

// ---------------------------------------------------------------------------
// kA: token argmax + LSTM1, tiled 8 row-tiles x 32 b-groups (verified round-1
// G1 math). Each block: 64 gate-rows x 8 batch elements, weight slice (80 KB)
// staged in LDS, 8x batch reuse. h1 parity double-buffered (intra-dispatch
// readers of h1prev race with writers of h1new otherwise); c1 slice private.
// ---------------------------------------------------------------------------
__global__ __launch_bounds__(256) void kA(
    int t,
    const float* __restrict__ wts,
    float* __restrict__ h1g,           // [2][B][H1]
    float* __restrict__ c1g,           // [B][H1]
    const float* __restrict__ ctxg,    // [B][D]
    const float* __restrict__ candv, const int* __restrict__ candi)
{
  const int bid = blockIdx.x;
  const int tid = threadIdx.x;
  const int rt = bid >> 5;         // 0..7 row-tile (16 units x 4 gates)
  const int bA = (bid & 31) * 8;   // batch base

  __shared__ float4 wA4[80*64];              // 80 KB [k4][r]
  __shared__ __align__(16) float xs[8*324];  // xcat per b (320 used, pad 324)
  __shared__ float g_s[64*8];
  __shared__ float bias1_s[64];
  __shared__ int tok_s[8];

  const int par = t & 1;
  const float* h1prev = h1g + (size_t)(par^1)*B*H1;
  float*       h1new  = h1g + (size_t)par*B*H1;

  // ---- stage weight slice (overlaps with argmax below; one sync covers) ----
  for (int idx = tid; idx < 80*64; idx += 256){
    const int k4 = idx >> 6, r = idx & 63;
    const int row = ((r >> 4) * 128) + (rt * 16) + (r & 15);
    float4 w;
    if (k4 < 48) w = ldf4(wts + O_WIH1 + (size_t)row*(E+D) + k4*4);
    else         w = ldf4(wts + O_WHH1 + (size_t)row*H1 + (k4-48)*4);
    wA4[idx] = w;
  }
  if (tid < 64){
    const int rowA = ((tid >> 4) * 128) + (rt * 16) + (tid & 15);
    bias1_s[tid] = wts[O_BIH1 + rowA] + wts[O_BHH1 + rowA];
  }

  // ---- token argmax over candidates (first-index tie-break) ----
  if (t > 0){
    const int bi = tid >> 5, j = tid & 31;
    const int b = bA + bi;
    float mv = candv[b*NVB + j];
    int   mi = candi[b*NVB + j];
    if (j < NVB - 32){
      float ov = candv[b*NVB + j + 32]; int oi = candi[b*NVB + j + 32];
      if (ov > mv || (ov == mv && oi < mi)){ mv = ov; mi = oi; }
    }
    #pragma unroll
    for (int off = 16; off > 0; off >>= 1){
      float ov = __shfl_down(mv, off); int oi = __shfl_down(mi, off);
      if (ov > mv || (ov == mv && oi < mi)){ mv = ov; mi = oi; }
    }
    if (j == 0) tok_s[bi] = mi;
  } else {
    if (tid < 8) tok_s[tid] = SOS;
  }
  __syncthreads();

  // ---- xcat = [emb(128) | ctx(64) | h1prev(128)] per b ----
  for (int bi = 0; bi < 8; ++bi){
    const int b = bA + bi;
    const int tok = tok_s[bi];
    for (int k = tid; k < 320; k += 256){
      float x;
      if (k < E)          x = (tok == EOS) ? 0.f : wts[O_EMB + (size_t)tok*E + k];
      else if (k < E + D) x = (t == 0) ? 0.f : ctxg[(size_t)b*D + (k - E)];
      else                x = (t == 0) ? 0.f : h1prev[(size_t)b*H1 + (k - (E + D))];
      xs[bi*324 + k] = x;
    }
  }
  __syncthreads();

  // ---- gates: 64 rows x 4 b-pairs ----
  {
    const int r = tid >> 2, bq = tid & 3;
    const float4* x0 = (const float4*)(xs + (bq*2    )*324);
    const float4* x1 = (const float4*)(xs + (bq*2 + 1)*324);
    float a0 = bias1_s[r], a1 = a0;
    #pragma unroll 8
    for (int k4 = 0; k4 < 80; ++k4){
      const float4 w = wA4[k4*64 + r];
      const float4 xa = x0[k4], xb = x1[k4];
      a0 += xa.x*w.x + xa.y*w.y + xa.z*w.z + xa.w*w.w;
      a1 += xb.x*w.x + xb.y*w.y + xb.z*w.z + xb.w*w.w;
    }
    g_s[r*8 + bq*2]     = a0;
    g_s[r*8 + bq*2 + 1] = a1;
  }
  __syncthreads();

  // ---- update: 16 units x 8 b ----
  if (tid < 128){
    const int ui = tid >> 3, bi = tid & 7;
    const float gi = sigf (g_s[(ui     )*8 + bi]);
    const float gf = sigf (g_s[(16 + ui)*8 + bi]);
    const float gg = tanhf(g_s[(32 + ui)*8 + bi]);
    const float go = sigf (g_s[(48 + ui)*8 + bi]);
    const float cold = (t == 0) ? 0.f : c1g[(size_t)(bA + bi)*H1 + rt*16 + ui];
    const float cn = gf * cold + gi * gg;
    c1g[(size_t)(bA + bi)*H1 + rt*16 + ui] = cn;
    h1new[(size_t)(bA + bi)*H1 + rt*16 + ui] = go * tanhf(cn);
  }
}

// ---------------------------------------------------------------------------
// kB: per-b LSTM2 + query + masked-softmax attention + context (baseline kdec
// math, fp32 encT streaming as verified in round-1 G3). One block per b.
// h2/c2/ctx are block-private slices -> single-buffered.
// ---------------------------------------------------------------------------
__global__ __launch_bounds__(256) void kB(
    int t,
    const float* __restrict__ wts,
    const float* __restrict__ encTk, const float* __restrict__ encTv,
    const int* __restrict__ mask,
    const float* __restrict__ h1g,     // [2][B][H1]
    float* __restrict__ h2g,           // [B][H2]
    float* __restrict__ c2g,           // [B][H2]
    float* __restrict__ ctxg,          // [B][D]
    float* __restrict__ xvec)          // [B][H2+D]
{
  const int b = blockIdx.x;
  const int tid = threadIdx.x;
  const float* h1new = h1g + (size_t)(t & 1)*B*H1;

  __shared__ float h1_s[H1];
  __shared__ float h2_s[H2];
  __shared__ float h2n_s[H2];
  __shared__ float g_s[4*H2];
  __shared__ float q_s[D];
  __shared__ float wv_s[T];
  __shared__ float red_s[256];

  if (tid < H1)                h1_s[tid]      = h1new[(size_t)b*H1 + tid];
  else if (tid < H1 + H2)      h2_s[tid - H1] = (t == 0) ? 0.f : h2g[(size_t)b*H2 + (tid - H1)];
  __syncthreads();

  // ---- LSTM2 gates (256 outputs, 1 per thread) ----
  {
    const int j = tid;
    const float* wr = wts + O_WIH2 + (size_t)j*H1;
    float acc = wts[O_BIH2 + j] + wts[O_BHH2 + j];
    #pragma unroll
    for (int kk = 0; kk < H1/4; ++kk) acc += dot4f(h1_s + kk*4, ldf4(wr + kk*4));
    const float* wr2 = wts + O_WHH2 + (size_t)j*H2;
    #pragma unroll
    for (int kk = 0; kk < H2/4; ++kk) acc += dot4f(h2_s + kk*4, ldf4(wr2 + kk*4));
    g_s[j] = acc;
  }
  __syncthreads();

  // ---- LSTM2 update ----
  if (tid < H2){
    const float gi = sigf(g_s[tid]);
    const float gf = sigf(g_s[H2 + tid]);
    const float gg = tanhf(g_s[2*H2 + tid]);
    const float go = sigf(g_s[3*H2 + tid]);
    const float cold = (t == 0) ? 0.f : c2g[(size_t)b*H2 + tid];
    const float cn = gf*cold + gi*gg;
    const float hn = go*tanhf(cn);
    c2g[(size_t)b*H2 + tid] = cn;
    h2g[(size_t)b*H2 + tid] = hn;
    h2n_s[tid] = hn;
    xvec[(size_t)b*(H2 + D) + tid] = hn;
  }
  __syncthreads();

  // ---- query = h2_new @ wq.T + bq ----
  if (tid < D){
    const float* wr = wts + O_WQ + (size_t)tid*H2;
    float acc = wts[O_BQ + tid];
    #pragma unroll
    for (int kk = 0; kk < H2/4; ++kk) acc += dot4f(h2n_s + kk*4, ldf4(wr + kk*4));
    q_s[tid] = acc;
  }
  __syncthreads();

  // ---- attention energies for t2 = tid and tid+256 (fp32 encT) ----
  float e0 = 0.f, e1 = 0.f;
  {
    const float* kr0 = encTk + ((size_t)b*T + tid)*D;
    const float* kr1 = kr0 + (size_t)256*D;
    #pragma unroll
    for (int kk = 0; kk < D/4; ++kk){
      e0 += dot4f(q_s + kk*4, ldf4(kr0 + kk*4));
      e1 += dot4f(q_s + kk*4, ldf4(kr1 + kk*4));
    }
  }
  red_s[tid] = fmaxf(e0, e1);
  __syncthreads();
  for (int s = 128; s > 0; s >>= 1){
    if (tid < s) red_s[tid] = fmaxf(red_s[tid], red_s[tid + s]);
    __syncthreads();
  }
  const float emax = red_s[0];
  __syncthreads();

  const int m0 = mask[b*T + tid], m1 = mask[b*T + tid + 256];
  const float w0 = m0 ? expf(e0 - emax) : 0.f;
  const float w1 = m1 ? expf(e1 - emax) : 0.f;
  wv_s[tid] = w0;
  wv_s[tid + 256] = w1;
  red_s[tid] = w0 + w1;
  __syncthreads();
  for (int s = 128; s > 0; s >>= 1){
    if (tid < s) red_s[tid] += red_s[tid + s];
    __syncthreads();
  }
  const float inv = 1.f / fmaxf(red_s[0], 2e-30f);
  __syncthreads();

  // ---- context = (w/sum) . enc_values ----
  {
    const int d = tid & 63, ch = tid >> 6;
    const float* vb2 = encTv + (size_t)b*T*D + d;
    float acc = 0.f;
    #pragma unroll 8
    for (int tt = ch*128; tt < ch*128 + 128; ++tt)
      acc += wv_s[tt] * vb2[(size_t)tt*D];
    red_s[tid] = acc;
  }
  __syncthreads();
  if (tid < D){
    const float cv = (red_s[tid] + red_s[tid+64] + red_s[tid+128] + red_s[tid+192]) * inv;
    ctxg[(size_t)b*D + tid] = cv;
    xvec[(size_t)b*(H2 + D) + H2 + tid] = cv;
  }
}

// ---------------------------------------------------------------------------
// kC: pred = xvec @ wp.T + bp, fused store + per-(b, v-block) argmax candidate
// (baseline kpred, verified). grid (NVB x B/BGS), 256 threads.
// ---------------------------------------------------------------------------
__global__ __launch_bounds__(256) void kC(
    int t,
    const float* __restrict__ wp_f,
    const float* __restrict__ bp_f,
    const float* __restrict__ xvec,
    void* __restrict__ outv,
    float* __restrict__ candv, int* __restrict__ candi,
    const int* __restrict__ flagp)
{
  const int tid = threadIdx.x;
  const int vb = blockIdx.x;
  const int v = vb * 256 + tid;
  const int bg = blockIdx.y;
  const int flagb = flagp[0];
  const bool valid = v < V;
  const int vc = valid ? v : 0;
  const float* wrow = wp_f + (size_t)vc*(H2 + D);
  const float* xp = xvec + (size_t)bg*BGS*(H2 + D);

  float acc[BGS];
  #pragma unroll
  for (int i = 0; i < BGS; ++i) acc[i] = 0.f;

  #pragma unroll
  for (int kk = 0; kk < (H2 + D)/4; ++kk){
    const float4 w = ldf4(wrow + kk*4);
    #pragma unroll
    for (int i = 0; i < BGS; ++i){
      const float* x = xp + i*(H2 + D) + kk*4;
      acc[i] += x[0]*w.x + x[1]*w.y + x[2]*w.z + x[3]*w.w;
    }
  }

  const float bias = valid ? bp_f[vc] : 0.f;
  #pragma unroll
  for (int i = 0; i < BGS; ++i){
    acc[i] += bias;
    if (valid){
      const size_t oi = ((size_t)(bg*BGS + i)*MAXLEN + t)*V + v;
      if (flagb) ((__hip_bfloat16*)outv)[oi] = __float2bfloat16(acc[i]);
      else       ((float*)outv)[oi] = acc[i];
    }
  }

  // per-b (val, idx) max with first-index tie-break: wave shuffle -> LDS -> ws
  __shared__ float lv[4][BGS];
  __shared__ int   li[4][BGS];
  const int lane = tid & 63, wid = tid >> 6;
  #pragma unroll
  for (int i = 0; i < BGS; ++i){
    float mv = valid ? acc[i] : -__builtin_inff();
    int   mi = valid ? v : 0x7FFFFFFF;
    for (int off = 32; off > 0; off >>= 1){
      float ov = __shfl_down(mv, off);
      int   oi = __shfl_down(mi, off);
      if (ov > mv || (ov == mv && oi < mi)){ mv = ov; mi = oi; }
    }
    if (lane == 0){ lv[wid][i] = mv; li[wid][i] = mi; }
  }
  __syncthreads();
  if (tid < BGS){
    float mv = lv[0][tid]; int mi = li[0][tid];
    #pragma unroll
    for (int w2 = 1; w2 < 4; ++w2){
      float ov = lv[w2][tid]; int oi = li[w2][tid];
      if (ov > mv || (ov == mv && oi < mi)){ mv = ov; mi = oi; }
    }
    const int b = bg*BGS + tid;
    candv[b*NVB + vb] = mv;
    candi[b*NVB + vb] = mi;
  }
}

// ---------------------------------------------------------------------------
extern "C" void kernel_launch(void* const* d_in, const int* in_sizes, int n_in,
                              void* d_out, int out_size, void* d_ws, size_t ws_size,
                              hipStream_t stream)
{
  const void* enc_key = d_in[0];
  const void* enc_val = d_in[1];
  const int*  mask    = (const int*)d_in[2];
  const void* emb     = d_in[3];
  const void* w_ih1   = d_in[4];
  const void* w_hh1   = d_in[5];
  const void* b_ih1   = d_in[6];
  const void* b_hh1   = d_in[7];
  const void* w_ih2   = d_in[8];
  const void* w_hh2   = d_in[9];
  const void* b_ih2   = d_in[10];
  const void* b_hh2   = d_in[11];
  const void* wq      = d_in[12];
  const void* bq      = d_in[13];
  const void* wp      = d_in[14];
  const void* bp      = d_in[15];

  // ws layout: [flag 16f][wts TOTALW][h1g 2*B*H1][c1g B*H1][h2g B*H2]
  //            [c2g B*H2][ctx B*D][xvec B*(H2+D)][candv][candi][encTk][encTv]
  float* wsf  = (float*)d_ws;
  int*  flagp = (int*)wsf;
  float* wts  = wsf + 16;
  float* h1g   = wts + TOTALW;
  float* c1g   = h1g + 2*B*H1;
  float* h2g   = c1g + B*H1;
  float* c2g   = h2g + B*H2;
  float* ctxg  = c2g + B*H2;
  float* xvec  = ctxg + B*D;
  float* candv = xvec + B*(H2 + D);
  int*   candi = (int*)(candv + B*NVB);
  float* encTk = (float*)(candi + B*NVB);
  float* encTv = encTk + (size_t)B*T*D;

  kdtype<<<dim3(1), dim3(64), 0, stream>>>(b_ih1, flagp);
  kcvt<<<dim3((TOTALW + 255)/256), dim3(256), 0, stream>>>(
      emb, w_ih1, w_hh1, b_ih1, b_hh1, w_ih2, w_hh2, b_ih2, b_hh2,
      wq, bq, wp, bp, wts, flagp);
  ktrans<<<dim3(B), dim3(256), 0, stream>>>(enc_key, enc_val, encTk, encTv, flagp);

  for (int t = 0; t < MAXLEN; ++t){
    kA<<<dim3(B), dim3(256), 0, stream>>>(
        t, wts, h1g, c1g, ctxg, candv, candi);
    kB<<<dim3(B), dim3(256), 0, stream>>>(
        t, wts, encTk, encTv, mask, h1g, h2g, c2g, ctxg, xvec);
    kC<<<dim3(NVB, B/BGS), dim3(256), 0, stream>>>(
        t, wts + O_WP, wts + O_BP, xvec, d_out, candv, candi, flagp);
  }
}